// Round 1
// baseline (1230.287 us; speedup 1.0000x reference)
//
#include <hip/hip_runtime.h>
#include <hip/hip_bf16.h>

// ---------------------------------------------------------------------------
// TransformerEncoder3D: N=131072 tokens, E=128, 3 layers
//   per layer: x += Proj(Attn(IN(x))) ; x += FFN2(hswish(FFN1(IN(x))))
// InstanceNorm (stats over tokens per channel) folded into GEMM A-staging as
// per-channel affine. All GEMMs bf16 MFMA 16x16x32. Attention: 1 wave/head,
// Z=32, head dim 128, E^T = K@Q^T trick for in-lane softmax.
// ---------------------------------------------------------------------------

typedef __attribute__((ext_vector_type(8))) short bf16x8;
typedef __attribute__((ext_vector_type(4))) float f32x4;
typedef __attribute__((ext_vector_type(4))) float fvec4;

#define N_TOK 131072

__device__ __forceinline__ unsigned short f2bf(float f) {
  unsigned u = __builtin_bit_cast(unsigned, f);
  u += 0x7FFFu + ((u >> 16) & 1u);          // round-to-nearest-even
  return (unsigned short)(u >> 16);
}

__device__ __forceinline__ f32x4 mfma16(bf16x8 a, bf16x8 b, f32x4 c) {
  return __builtin_amdgcn_mfma_f32_16x16x32_bf16(a, b, c, 0, 0, 0);
}

// ---------------------------------------------------------------------------
// Weight prep: bf16 + transpose (B^T layout [Nout][K]) + qkv column de-interleave
// ---------------------------------------------------------------------------
__global__ __launch_bounds__(256) void prep_kernel(
    const float* __restrict__ Wqkv, const float* __restrict__ bqkv,
    const float* __restrict__ Wproj, const float* __restrict__ W1,
    const float* __restrict__ W2,
    unsigned short* __restrict__ WqT, unsigned short* __restrict__ WpT,
    unsigned short* __restrict__ W1T, unsigned short* __restrict__ W2T,
    float* __restrict__ bqp)
{
  const int idx = blockIdx.x * 256 + threadIdx.x;
  const int PER = 196608;
  if (idx < 3 * PER) {
    const int d = idx / PER, r = idx % PER;
    if (r < 49152) {                       // WqT[d][384][128], col c = which*128+e
      const int c = r >> 7, k = r & 127;
      WqT[d * 49152 + r] = f2bf(Wqkv[(size_t)d * 49152 + k * 384 + ((c & 127) * 3 + (c >> 7))]);
    } else if (r < 65536) {                // WpT[d][128][128]
      const int r2 = r - 49152; const int c = r2 >> 7, k = r2 & 127;
      WpT[d * 16384 + r2] = f2bf(Wproj[(size_t)d * 16384 + k * 128 + c]);
    } else if (r < 131072) {               // W1T[d][512][128]
      const int r3 = r - 65536; const int c = r3 >> 7, k = r3 & 127;
      W1T[d * 65536 + r3] = f2bf(W1[(size_t)d * 65536 + k * 512 + c]);
    } else {                               // W2T[d][128][512]
      const int r4 = r - 131072; const int c = r4 >> 9, k = r4 & 511;
      W2T[d * 65536 + r4] = f2bf(W2[(size_t)d * 65536 + k * 128 + c]);
    }
  } else if (idx < 3 * PER + 1152) {
    const int i2 = idx - 3 * PER; const int d = i2 / 384, c = i2 % 384;
    bqp[i2] = bqkv[d * 384 + (c & 127) * 3 + (c >> 7)];
  }
}

// ---------------------------------------------------------------------------
// img [128][131072] f32 -> x [131072][128] f32
// ---------------------------------------------------------------------------
__global__ __launch_bounds__(256) void tin_kernel(const float* __restrict__ img,
                                                  float* __restrict__ x)
{
  __shared__ float t[128 * 65];
  const int t0 = blockIdx.x * 64;
  const int tid = threadIdx.x;
  {
    const int j = tid & 63, cq = tid >> 6;
    for (int c = cq; c < 128; c += 4) t[c * 65 + j] = img[(size_t)c * N_TOK + t0 + j];
  }
  __syncthreads();
  {
    const int c = tid & 127, jh = tid >> 7;
    for (int jj = jh; jj < 64; jj += 2) x[(size_t)(t0 + jj) * 128 + c] = t[c * 65 + jj];
  }
}

// x [131072][128] -> out [128][131072] with relu
__global__ __launch_bounds__(256) void tout_kernel(const float* __restrict__ x,
                                                   float* __restrict__ out)
{
  __shared__ float t[128 * 65];
  const int t0 = blockIdx.x * 64;
  const int tid = threadIdx.x;
  {
    const int c = tid & 127, jh = tid >> 7;
    for (int jj = jh; jj < 64; jj += 2) t[c * 65 + jj] = x[(size_t)(t0 + jj) * 128 + c];
  }
  __syncthreads();
  {
    const int j = tid & 63, cq = tid >> 6;
    for (int c = cq; c < 128; c += 4)
      out[(size_t)c * N_TOK + t0 + j] = fmaxf(t[c * 65 + j], 0.f);
  }
}

// ---------------------------------------------------------------------------
// Column stats over tokens: accum[0..127]=sum, accum[128..255]=sumsq
// ---------------------------------------------------------------------------
__global__ __launch_bounds__(256) void colstats_kernel(const float* __restrict__ x,
                                                       float* __restrict__ accum)
{
  __shared__ float red[2048];
  const int tid = threadIdx.x;
  const int c4 = (tid & 31) << 2;
  const int rg = tid >> 5;                 // 0..7
  float s0 = 0, s1 = 0, s2 = 0, s3 = 0, q0 = 0, q1 = 0, q2 = 0, q3 = 0;
  const size_t rbase = (size_t)blockIdx.x * 256;
  for (int r = rg; r < 256; r += 8) {
    fvec4 v = *(const fvec4*)&x[(rbase + r) * 128 + c4];
    s0 += v[0]; q0 += v[0] * v[0];
    s1 += v[1]; q1 += v[1] * v[1];
    s2 += v[2]; q2 += v[2] * v[2];
    s3 += v[3]; q3 += v[3] * v[3];
  }
  red[rg * 128 + c4 + 0] = s0; red[rg * 128 + c4 + 1] = s1;
  red[rg * 128 + c4 + 2] = s2; red[rg * 128 + c4 + 3] = s3;
  red[1024 + rg * 128 + c4 + 0] = q0; red[1024 + rg * 128 + c4 + 1] = q1;
  red[1024 + rg * 128 + c4 + 2] = q2; red[1024 + rg * 128 + c4 + 3] = q3;
  __syncthreads();
  const int c = tid & 127, which = tid >> 7;
  float t = 0.f;
#pragma unroll
  for (int g = 0; g < 8; ++g) t += red[which * 1024 + g * 128 + c];
  atomicAdd(&accum[(which << 7) + c], t);
}

__global__ void finalize_kernel(const float* __restrict__ accum, const float* __restrict__ g,
                                const float* __restrict__ b, float* __restrict__ st)
{
  const int c = threadIdx.x;
  const float inv = 1.f / 131072.f;
  const float mu = accum[c] * inv;
  const float var = accum[128 + c] * inv - mu * mu;
  const float s = g[c] * rsqrtf(var + 1e-5f);
  st[c] = s;
  st[128 + c] = b[c] - mu * s;
}

// ---------------------------------------------------------------------------
// GEMM: C[M=131072, NOUT] = A[M, KTOT] @ B[KTOT, NOUT] + bias (+ epilogue)
//  AMODE 0: A fp32 with per-channel affine (LN fold); AMODE 1: A bf16
//  EP 0: qkv -> per-head [h][z][e] bf16 buffers (q/k/v by col-tile)
//  EP 1: f32 in-place residual add (Cptr = x)
//  EP 2: hard_swish -> bf16 (stride NOUT)
// ---------------------------------------------------------------------------
template <int AMODE, int EP, int KTOT, int NOUT>
__global__ __launch_bounds__(256) void gemm_kernel(
    const void* __restrict__ Aptr,
    const unsigned short* __restrict__ BT,   // [NOUT][KTOT] bf16
    const float* __restrict__ bias,
    void* __restrict__ Cptr,
    const float* __restrict__ st)            // [256]: s, t
{
  __shared__ unsigned short As[128 * 64];
  __shared__ unsigned short Bs[128 * 64];
  const int tid = threadIdx.x;
  const int lane = tid & 63, wave = tid >> 6;
  const int brow = blockIdx.x << 7, bcol = blockIdx.y << 7;
  const int lr = lane & 15, lg = lane >> 4;
  const int wr = wave >> 1, wc = wave & 1;
  const int srow = tid >> 1, shalf = tid & 1;

  f32x4 acc[4][4];
#pragma unroll
  for (int m = 0; m < 4; ++m)
#pragma unroll
    for (int n = 0; n < 4; ++n) acc[m][n] = (f32x4){0.f, 0.f, 0.f, 0.f};

  for (int kt = 0; kt < KTOT / 64; ++kt) {
    if (kt) __syncthreads();
    const int k0 = kt * 64 + shalf * 32;
    if (AMODE == 0) {
      const float* xr = (const float*)Aptr + (size_t)(brow + srow) * KTOT + k0;
#pragma unroll
      for (int cc = 0; cc < 4; ++cc) {
        fvec4 v0 = *(const fvec4*)(xr + cc * 8);
        fvec4 v1 = *(const fvec4*)(xr + cc * 8 + 4);
        fvec4 sA = *(const fvec4*)(st + k0 + cc * 8);
        fvec4 sB = *(const fvec4*)(st + k0 + cc * 8 + 4);
        fvec4 tA = *(const fvec4*)(st + 128 + k0 + cc * 8);
        fvec4 tB = *(const fvec4*)(st + 128 + k0 + cc * 8 + 4);
        bf16x8 w;
#pragma unroll
        for (int j = 0; j < 4; ++j) w[j] = (short)f2bf(v0[j] * sA[j] + tA[j]);
#pragma unroll
        for (int j = 0; j < 4; ++j) w[4 + j] = (short)f2bf(v1[j] * sB[j] + tB[j]);
        const int ch = shalf * 4 + cc;
        *(bf16x8*)&As[(srow << 6) + ((ch ^ (srow & 7)) << 3)] = w;
      }
    } else {
      const unsigned short* ar = (const unsigned short*)Aptr + (size_t)(brow + srow) * KTOT + k0;
#pragma unroll
      for (int cc = 0; cc < 4; ++cc) {
        bf16x8 w = *(const bf16x8*)(ar + cc * 8);
        const int ch = shalf * 4 + cc;
        *(bf16x8*)&As[(srow << 6) + ((ch ^ (srow & 7)) << 3)] = w;
      }
    }
    {
      const unsigned short* br = BT + (size_t)(bcol + srow) * KTOT + k0;
#pragma unroll
      for (int cc = 0; cc < 4; ++cc) {
        bf16x8 w = *(const bf16x8*)(br + cc * 8);
        const int ch = shalf * 4 + cc;
        *(bf16x8*)&Bs[(srow << 6) + ((ch ^ (srow & 7)) << 3)] = w;
      }
    }
    __syncthreads();
#pragma unroll
    for (int kk = 0; kk < 2; ++kk) {
      bf16x8 af[4], bfr[4];
#pragma unroll
      for (int m = 0; m < 4; ++m) {
        const int r = (wr << 6) + (m << 4) + lr;
        const int ch = (kk << 2) + lg;
        af[m] = *(const bf16x8*)&As[(r << 6) + ((ch ^ (r & 7)) << 3)];
      }
#pragma unroll
      for (int n = 0; n < 4; ++n) {
        const int c = (wc << 6) + (n << 4) + lr;
        const int ch = (kk << 2) + lg;
        bfr[n] = *(const bf16x8*)&Bs[(c << 6) + ((ch ^ (c & 7)) << 3)];
      }
#pragma unroll
      for (int m = 0; m < 4; ++m)
#pragma unroll
        for (int n = 0; n < 4; ++n)
          acc[m][n] = mfma16(af[m], bfr[n], acc[m][n]);
    }
  }

#pragma unroll
  for (int n = 0; n < 4; ++n) {
    const int col = bcol + (wc << 6) + (n << 4) + lr;
    const float bv = bias[col];
#pragma unroll
    for (int m = 0; m < 4; ++m) {
#pragma unroll
      for (int r = 0; r < 4; ++r) {
        const int row = brow + (wr << 6) + (m << 4) + (lg << 2) + r;
        const float v = acc[m][n][r] + bv;
        if (EP == 0) {
          const int z = row >> 12, hh = row & 4095;
          ((unsigned short*)Cptr)[((size_t)(col >> 7) << 24) + ((size_t)hh << 12) + (z << 7) + (col & 127)] = f2bf(v);
        } else if (EP == 1) {
          float* X = (float*)Cptr;
          const size_t idx = ((size_t)row << 7) + col;
          X[idx] = v + X[idx];
        } else {
          const float r6 = fminf(fmaxf(v + 3.f, 0.f), 6.f);
          ((unsigned short*)Cptr)[(size_t)row * NOUT + col] = f2bf(v * r6 * (1.f / 6.f));
        }
      }
    }
  }
}

// ---------------------------------------------------------------------------
// Attention: 1 wave per head. E^T = K@Q^T (so softmax over k is in-lane + 2
// shfl), P^T -> LDS (transposed to att[q][k]), V staged transposed in LDS.
// out rows are z*4096+head (row-preserving).
// ---------------------------------------------------------------------------
__global__ __launch_bounds__(256) void attn_kernel(
    const unsigned short* __restrict__ qbuf,
    const unsigned short* __restrict__ kbuf,
    const unsigned short* __restrict__ vbuf,
    unsigned short* __restrict__ aout)
{
  __shared__ unsigned short lds[4 * 6400];  // per wave: vT[128][40] + att[32][40]
  const int tid = threadIdx.x;
  const int lane = tid & 63, wave = tid >> 6;
  const int head = (blockIdx.x << 2) + wave;
  const int lr = lane & 15, lg = lane >> 4;
  const unsigned short* qh = qbuf + ((size_t)head << 12);
  const unsigned short* kh = kbuf + ((size_t)head << 12);
  const unsigned short* vh = vbuf + ((size_t)head << 12);
  unsigned short* vT = &lds[wave * 6400];
  unsigned short* attL = vT + 5120;

  // stage V transposed: vT[e][k], stride 40
#pragma unroll
  for (int i = 0; i < 4; ++i) {
    const int item = (i << 6) + lane;
    const int kzp = item >> 4;               // 0..15 (row pair)
    const int e0 = (item & 15) << 3;
    const bf16x8 v0 = *(const bf16x8*)&vh[((size_t)kzp << 8) + e0];
    const bf16x8 v1 = *(const bf16x8*)&vh[((size_t)kzp << 8) + 128 + e0];
#pragma unroll
    for (int j = 0; j < 8; ++j) {
      const unsigned w = (unsigned)(unsigned short)v0[j] | ((unsigned)(unsigned short)v1[j] << 16);
      *(unsigned*)&vT[(e0 + j) * 40 + (kzp << 1)] = w;
    }
  }

  // Q/K fragments direct from global (per-head contiguous [z][e])
  bf16x8 ka[2][4], qb2[2][4];
#pragma unroll
  for (int t = 0; t < 2; ++t)
#pragma unroll
    for (int kt = 0; kt < 4; ++kt) {
      const size_t ro = (size_t)((t << 4) + lr) << 7;
      ka[t][kt]  = *(const bf16x8*)&kh[ro + (kt << 5) + (lg << 3)];
      qb2[t][kt] = *(const bf16x8*)&qh[ro + (kt << 5) + (lg << 3)];
    }

  // E^T[kz][qz]
  f32x4 et[2][2];
#pragma unroll
  for (int mt = 0; mt < 2; ++mt)
#pragma unroll
    for (int nt = 0; nt < 2; ++nt) et[mt][nt] = (f32x4){0.f, 0.f, 0.f, 0.f};
#pragma unroll
  for (int kt = 0; kt < 4; ++kt)
#pragma unroll
    for (int mt = 0; mt < 2; ++mt)
#pragma unroll
      for (int nt = 0; nt < 2; ++nt)
        et[mt][nt] = mfma16(ka[mt][kt], qb2[nt][kt], et[mt][nt]);

  // softmax over kz (rows of E^T), then /sqrt(128), then *cm
  float p[2][2][4];
#pragma unroll
  for (int nt = 0; nt < 2; ++nt) {
    float mx = -1e30f;
#pragma unroll
    for (int mt = 0; mt < 2; ++mt)
#pragma unroll
      for (int r = 0; r < 4; ++r) mx = fmaxf(mx, et[mt][nt][r]);
    mx = fmaxf(mx, __shfl_xor(mx, 16));
    mx = fmaxf(mx, __shfl_xor(mx, 32));
    float s = 0.f;
#pragma unroll
    for (int mt = 0; mt < 2; ++mt)
#pragma unroll
      for (int r = 0; r < 4; ++r) {
        const float e = __expf(et[mt][nt][r] - mx);
        p[mt][nt][r] = e;
        s += e;
      }
    s += __shfl_xor(s, 16);
    s += __shfl_xor(s, 32);
    const float inv = 1.f / (s * 11.313708498984761f);  // sqrt(128)
    const int qz = (nt << 4) + lr;
#pragma unroll
    for (int mt = 0; mt < 2; ++mt)
#pragma unroll
      for (int r = 0; r < 4; ++r) {
        const int kz = (mt << 4) + (lg << 2) + r;
        const float d = (float)(kz - qz);
        p[mt][nt][r] *= inv * __expf(d * d * (-1.f / 16.f));
      }
  }

  // P^T -> att[q][k] in LDS (transpose on write, packed b64)
#pragma unroll
  for (int nt = 0; nt < 2; ++nt) {
    const int qz = (nt << 4) + lr;
#pragma unroll
    for (int mt = 0; mt < 2; ++mt) {
      const unsigned lo = (unsigned)f2bf(p[mt][nt][0]) | ((unsigned)f2bf(p[mt][nt][1]) << 16);
      const unsigned hi = (unsigned)f2bf(p[mt][nt][2]) | ((unsigned)f2bf(p[mt][nt][3]) << 16);
      const unsigned long long u = (unsigned long long)lo | ((unsigned long long)hi << 32);
      *(unsigned long long*)&attL[qz * 40 + (mt << 4) + (lg << 2)] = u;
    }
  }

  // PV: out[q][e] = att[q][:] @ V
  bf16x8 pa[2];
#pragma unroll
  for (int mt = 0; mt < 2; ++mt)
    pa[mt] = *(const bf16x8*)&attL[((mt << 4) + lr) * 40 + (lg << 3)];
#pragma unroll
  for (int nt = 0; nt < 8; ++nt) {
    const bf16x8 vb = *(const bf16x8*)&vT[((nt << 4) + lr) * 40 + (lg << 3)];
#pragma unroll
    for (int mt = 0; mt < 2; ++mt) {
      const f32x4 z = (f32x4){0.f, 0.f, 0.f, 0.f};
      const f32x4 ov = mfma16(pa[mt], vb, z);
#pragma unroll
      for (int r = 0; r < 4; ++r) {
        const int qz = (mt << 4) + (lg << 2) + r;
        aout[(((size_t)(qz << 12) + head) << 7) + (nt << 4) + lr] = f2bf(ov[r]);
      }
    }
  }
}

// ---------------------------------------------------------------------------
extern "C" void kernel_launch(void* const* d_in, const int* in_sizes, int n_in,
                              void* d_out, int out_size, void* d_ws, size_t ws_size,
                              hipStream_t stream)
{
  const float* img   = (const float*)d_in[0];
  const float* ln1g  = (const float*)d_in[1];
  const float* ln1b  = (const float*)d_in[2];
  const float* Wqkv  = (const float*)d_in[3];
  const float* bqkv  = (const float*)d_in[4];
  const float* Wproj = (const float*)d_in[5];
  const float* bproj = (const float*)d_in[6];
  const float* ln2g  = (const float*)d_in[7];
  const float* ln2b  = (const float*)d_in[8];
  const float* W1    = (const float*)d_in[9];
  const float* b1    = (const float*)d_in[10];
  const float* W2    = (const float*)d_in[11];
  const float* b2    = (const float*)d_in[12];

  char* ws = (char*)d_ws;
  float* x = (float*)ws;                                          // 64MB
  unsigned short* region = (unsigned short*)(ws + ((size_t)64 << 20));
  unsigned short* qbuf  = region;
  unsigned short* kbuf  = region + ((size_t)1 << 24);
  unsigned short* vbuf  = region + ((size_t)2 << 24);
  unsigned short* aoutb = region + ((size_t)3 << 24);
  unsigned short* hbuf  = region;                                 // overlap (disjoint lifetime)
  char* wsw = ws + ((size_t)192 << 20);
  unsigned short* WqT = (unsigned short*)wsw;                     // 3*49152
  unsigned short* WpT = WqT + 3 * 49152;                          // 3*16384
  unsigned short* W1T = WpT + 3 * 16384;                          // 3*65536
  unsigned short* W2T = W1T + 3 * 65536;                          // 3*65536
  float* bqp   = (float*)(W2T + 3 * 65536);                       // 3*384
  float* accum = bqp + 3 * 384;                                   // 256
  float* st    = accum + 256;                                     // 256

  prep_kernel<<<2309, 256, 0, stream>>>(Wqkv, bqkv, Wproj, W1, W2, WqT, WpT, W1T, W2T, bqp);
  tin_kernel<<<2048, 256, 0, stream>>>(img, x);

  for (int d = 0; d < 3; ++d) {
    hipMemsetAsync(accum, 0, 1024, stream);
    colstats_kernel<<<512, 256, 0, stream>>>(x, accum);
    finalize_kernel<<<1, 128, 0, stream>>>(accum, ln1g + d * 128, ln1b + d * 128, st);
    gemm_kernel<0, 0, 128, 384><<<dim3(1024, 3), 256, 0, stream>>>(
        x, WqT + d * 49152, bqp + d * 384, region, st);
    attn_kernel<<<1024, 256, 0, stream>>>(qbuf, kbuf, vbuf, aoutb);
    gemm_kernel<1, 1, 128, 128><<<dim3(1024, 1), 256, 0, stream>>>(
        aoutb, WpT + d * 16384, bproj + d * 128, x, st);
    hipMemsetAsync(accum, 0, 1024, stream);
    colstats_kernel<<<512, 256, 0, stream>>>(x, accum);
    finalize_kernel<<<1, 128, 0, stream>>>(accum, ln2g + d * 128, ln2b + d * 128, st);
    gemm_kernel<0, 2, 128, 512><<<dim3(1024, 4), 256, 0, stream>>>(
        x, W1T + d * 65536, b1 + d * 512, hbuf, st);
    gemm_kernel<1, 1, 512, 128><<<dim3(1024, 1), 256, 0, stream>>>(
        hbuf, W2T + d * 65536, b2 + d * 128, x, st);
  }

  tout_kernel<<<2048, 256, 0, stream>>>(x, (float*)d_out);
}

// Round 2
// 997.024 us; speedup vs baseline: 1.2340x; 1.2340x over previous
//
#include <hip/hip_runtime.h>
#include <hip/hip_bf16.h>

typedef __attribute__((ext_vector_type(8))) short bf16x8;
typedef __attribute__((ext_vector_type(4))) float f32x4;
typedef __attribute__((ext_vector_type(4))) float fvec4;
typedef unsigned short u16;
typedef unsigned int u32;
typedef unsigned long long u64;

#define N_TOK 131072

__device__ __forceinline__ u16 f2bf(float f) {
  u32 u = __builtin_bit_cast(u32, f);
  u += 0x7FFFu + ((u >> 16) & 1u);          // round-to-nearest-even
  return (u16)(u >> 16);
}

__device__ __forceinline__ f32x4 mfma16(bf16x8 a, bf16x8 b, f32x4 c) {
  return __builtin_amdgcn_mfma_f32_16x16x32_bf16(a, b, c, 0, 0, 0);
}

// swizzled index into a [128 rows][128 shorts] LDS tile: 16B-chunk XOR row&15
__device__ __forceinline__ int tix(int row, int s) {
  return (row << 7) + ((((s >> 3) ^ (row & 15))) << 3) + (s & 7);
}

// ---------------------------------------------------------------------------
// Weight prep (unchanged, verified): bf16 + transpose + qkv de-interleave
// ---------------------------------------------------------------------------
__global__ __launch_bounds__(256) void prep_kernel(
    const float* __restrict__ Wqkv, const float* __restrict__ bqkv,
    const float* __restrict__ Wproj, const float* __restrict__ W1,
    const float* __restrict__ W2,
    u16* __restrict__ WqT, u16* __restrict__ WpT,
    u16* __restrict__ W1T, u16* __restrict__ W2T,
    float* __restrict__ bqp)
{
  const int idx = blockIdx.x * 256 + threadIdx.x;
  const int PER = 196608;
  if (idx < 3 * PER) {
    const int d = idx / PER, r = idx % PER;
    if (r < 49152) {                       // WqT[d][384][128], row c = which*128+e
      const int c = r >> 7, k = r & 127;
      WqT[d * 49152 + r] = f2bf(Wqkv[(size_t)d * 49152 + k * 384 + ((c & 127) * 3 + (c >> 7))]);
    } else if (r < 65536) {                // WpT[d][128][128]
      const int r2 = r - 49152; const int c = r2 >> 7, k = r2 & 127;
      WpT[d * 16384 + r2] = f2bf(Wproj[(size_t)d * 16384 + k * 128 + c]);
    } else if (r < 131072) {               // W1T[d][512][128]
      const int r3 = r - 65536; const int c = r3 >> 7, k = r3 & 127;
      W1T[d * 65536 + r3] = f2bf(W1[(size_t)d * 65536 + k * 512 + c]);
    } else {                               // W2T[d][128][512]
      const int r4 = r - 131072; const int c = r4 >> 9, k = r4 & 511;
      W2T[d * 65536 + r4] = f2bf(W2[(size_t)d * 65536 + k * 128 + c]);
    }
  } else if (idx < 3 * PER + 1152) {
    const int i2 = idx - 3 * PER; const int d = i2 / 384, c = i2 % 384;
    bqp[i2] = bqkv[d * 384 + (c & 127) * 3 + (c >> 7)];
  }
}

// ---------------------------------------------------------------------------
// img [128][131072] f32 -> x [131072][128] f32
// ---------------------------------------------------------------------------
__global__ __launch_bounds__(256) void tin_kernel(const float* __restrict__ img,
                                                  float* __restrict__ x)
{
  __shared__ float t[128 * 65];
  const int t0 = blockIdx.x * 64;
  const int tid = threadIdx.x;
  {
    const int j = tid & 63, cq = tid >> 6;
    for (int c = cq; c < 128; c += 4) t[c * 65 + j] = img[(size_t)c * N_TOK + t0 + j];
  }
  __syncthreads();
  {
    const int c = tid & 127, jh = tid >> 7;
    for (int jj = jh; jj < 64; jj += 2) x[(size_t)(t0 + jj) * 128 + c] = t[c * 65 + jj];
  }
}

// x [131072][128] -> out [128][131072] with relu
__global__ __launch_bounds__(256) void tout_kernel(const float* __restrict__ x,
                                                   float* __restrict__ out)
{
  __shared__ float t[128 * 65];
  const int t0 = blockIdx.x * 64;
  const int tid = threadIdx.x;
  {
    const int c = tid & 127, jh = tid >> 7;
    for (int jj = jh; jj < 64; jj += 2) t[c * 65 + jj] = x[(size_t)(t0 + jj) * 128 + c];
  }
  __syncthreads();
  {
    const int j = tid & 63, cq = tid >> 6;
    for (int c = cq; c < 128; c += 4)
      out[(size_t)c * N_TOK + t0 + j] = fmaxf(t[c * 65 + j], 0.f);
  }
}

// ---------------------------------------------------------------------------
// Column stats over tokens (used once, for initial LN1)
// ---------------------------------------------------------------------------
__global__ __launch_bounds__(256) void colstats_kernel(const float* __restrict__ x,
                                                       float* __restrict__ accum)
{
  __shared__ float red[2048];
  const int tid = threadIdx.x;
  const int c4 = (tid & 31) << 2;
  const int rg = tid >> 5;
  float s0 = 0, s1 = 0, s2 = 0, s3 = 0, q0 = 0, q1 = 0, q2 = 0, q3 = 0;
  const size_t rbase = (size_t)blockIdx.x * 256;
  for (int r = rg; r < 256; r += 8) {
    fvec4 v = *(const fvec4*)&x[(rbase + r) * 128 + c4];
    s0 += v[0]; q0 += v[0] * v[0];
    s1 += v[1]; q1 += v[1] * v[1];
    s2 += v[2]; q2 += v[2] * v[2];
    s3 += v[3]; q3 += v[3] * v[3];
  }
  red[rg * 128 + c4 + 0] = s0; red[rg * 128 + c4 + 1] = s1;
  red[rg * 128 + c4 + 2] = s2; red[rg * 128 + c4 + 3] = s3;
  red[1024 + rg * 128 + c4 + 0] = q0; red[1024 + rg * 128 + c4 + 1] = q1;
  red[1024 + rg * 128 + c4 + 2] = q2; red[1024 + rg * 128 + c4 + 3] = q3;
  __syncthreads();
  const int c = tid & 127, which = tid >> 7;
  float t = 0.f;
#pragma unroll
  for (int g = 0; g < 8; ++g) t += red[which * 1024 + g * 128 + c];
  atomicAdd(&accum[(which << 7) + c], t);
}

__global__ void finalize_kernel(const float* __restrict__ accum, const float* __restrict__ g,
                                const float* __restrict__ b, float* __restrict__ st)
{
  const int c = threadIdx.x;
  const float inv = 1.f / 131072.f;
  const float mu = accum[c] * inv;
  const float var = accum[128 + c] * inv - mu * mu;
  const float s = g[c] * rsqrtf(var + 1e-5f);
  st[c] = s;
  st[128 + c] = b[c] - mu * s;
}

// ---------------------------------------------------------------------------
// Shared device helpers
// ---------------------------------------------------------------------------
__device__ __forceinline__ void stageB(u16* __restrict__ Bs, const u16* __restrict__ BT,
                                       int srow, int shalf) {
  const u16* br = BT + (srow << 7) + (shalf << 6);
#pragma unroll
  for (int cc = 0; cc < 8; ++cc)
    *(bf16x8*)&Bs[tix(srow, (shalf << 6) + cc * 8)] = *(const bf16x8*)(br + cc * 8);
}

// A [128][128] swizzled LDS, B [128 cols][128 k] swizzled LDS ("B^T" layout).
// Wave computes rows woff..woff+31 x cols 0..127, K=128. acc zero-inited.
__device__ __forceinline__ void gemm_32x128(const u16* __restrict__ A, const u16* __restrict__ B,
                                            int woff, int lr, int lg, f32x4 acc[2][8]) {
#pragma unroll
  for (int mt = 0; mt < 2; ++mt)
#pragma unroll
    for (int n = 0; n < 8; ++n) acc[mt][n] = (f32x4){0.f, 0.f, 0.f, 0.f};
#pragma unroll
  for (int kk = 0; kk < 4; ++kk) {
    bf16x8 af[2], bfr[8];
    const int ks = (kk << 5) + (lg << 3);
#pragma unroll
    for (int mt = 0; mt < 2; ++mt)
      af[mt] = *(const bf16x8*)&A[tix(woff + (mt << 4) + lr, ks)];
#pragma unroll
    for (int n = 0; n < 8; ++n)
      bfr[n] = *(const bf16x8*)&B[tix((n << 4) + lr, ks)];
#pragma unroll
    for (int mt = 0; mt < 2; ++mt)
#pragma unroll
      for (int n = 0; n < 8; ++n)
        acc[mt][n] = mfma16(af[mt], bfr[n], acc[mt][n]);
  }
}

// ---------------------------------------------------------------------------
// Fused attention half-layer: block = 4 heads (h0..h0+3) x 32 z = 128 tokens.
//   qkv GEMMs (LN1 folded) -> in-LDS attention -> proj GEMM -> residual ->
//   LN2 column stats (atomics).
// ---------------------------------------------------------------------------
__global__ __launch_bounds__(256, 1) void attn_fused_kernel(
    const u16* __restrict__ WqTall,       // [384][128]: rows 0-127 Wq, 128-255 Wk, 256-383 Wv
    const float* __restrict__ bqp,        // [384]
    const u16* __restrict__ WpT,          // [128][128]
    const float* __restrict__ bp,         // [128]
    const float* __restrict__ st,         // [256] LN1 fold: s, t
    float* __restrict__ accum,            // [256] LN2 stats out
    float* __restrict__ x)                // [131072][128] read + update
{
  __shared__ u16 buf0[16384];  // As -> qL -> aoutL
  __shared__ u16 buf1[16384];  // Bs: Wv, Wk, Wq, Wp
  __shared__ u16 buf2[16384];  // kL -> attL (per-wave 1024 shorts)
  __shared__ u16 buf3[16384];  // vT [4 heads][128 e][32 kz] (chunk-swizzled)
  __shared__ float sred[256];

  const int tid = threadIdx.x;
  const int lane = tid & 63, wave = tid >> 6;
  const int lr = lane & 15, lg = lane >> 4;
  const int h0 = blockIdx.x << 2;
  const int srow = tid >> 1, shalf = tid & 1;
  const int woff = wave << 5;

  sred[tid] = 0.f;

  // --- stage A (LN1-folded bf16) ---
  {
    const int grow = ((srow >> 2) << 12) + h0 + (srow & 3);
    const float* xr = x + ((size_t)grow << 7) + (shalf << 6);
    const int s0 = shalf << 6;
#pragma unroll
    for (int cc = 0; cc < 8; ++cc) {
      fvec4 v0 = *(const fvec4*)(xr + cc * 8);
      fvec4 v1 = *(const fvec4*)(xr + cc * 8 + 4);
      fvec4 sA = *(const fvec4*)(st + s0 + cc * 8);
      fvec4 sB = *(const fvec4*)(st + s0 + cc * 8 + 4);
      fvec4 tA = *(const fvec4*)(st + 128 + s0 + cc * 8);
      fvec4 tB = *(const fvec4*)(st + 128 + s0 + cc * 8 + 4);
      bf16x8 w;
#pragma unroll
      for (int j = 0; j < 4; ++j) w[j] = (short)f2bf(v0[j] * sA[j] + tA[j]);
#pragma unroll
      for (int j = 0; j < 4; ++j) w[4 + j] = (short)f2bf(v1[j] * sB[j] + tB[j]);
      *(bf16x8*)&buf0[tix(srow, s0 + cc * 8)] = w;
    }
  }
  stageB(buf1, WqTall + 2 * 16384, srow, shalf);   // Wv
  __syncthreads();

  // --- V = A @ Wv, write transposed into vT ---
  {
    f32x4 vacc[2][8];
    gemm_32x128(buf0, buf1, woff, lr, lg, vacc);
    const float* bv = bqp + 256;
#pragma unroll
    for (int n = 0; n < 8; ++n) {
      const int e = (n << 4) + lr;
      const float bb = bv[e];
      const int sw = (e >> 1) & 3;
#pragma unroll
      for (int mt = 0; mt < 2; ++mt) {
        const int z = (wave << 3) + (mt << 2) + lg;
        const int zaddr = (((z >> 3) ^ sw) << 3) + (z & 7);
#pragma unroll
        for (int rr = 0; rr < 4; ++rr)
          buf3[(rr << 12) + (e << 5) + zaddr] = f2bf(vacc[mt][n][rr] + bb);
      }
    }
  }
  __syncthreads();

  // --- K = A @ Wk -> kL[head*32+z][e] ---
  stageB(buf1, WqTall + 16384, srow, shalf);       // Wk
  __syncthreads();
  {
    f32x4 kacc[2][8];
    gemm_32x128(buf0, buf1, woff, lr, lg, kacc);
    const float* bk = bqp + 128;
#pragma unroll
    for (int n = 0; n < 8; ++n) {
      const int e = (n << 4) + lr;
      const float bb = bk[e];
#pragma unroll
      for (int mt = 0; mt < 2; ++mt) {
        const int z = (wave << 3) + (mt << 2) + lg;
#pragma unroll
        for (int rr = 0; rr < 4; ++rr)
          buf2[tix((rr << 5) + z, e)] = f2bf(kacc[mt][n][rr] + bb);
      }
    }
  }
  __syncthreads();

  // --- Q = A @ Wq (kept in regs until buf0 free) ---
  stageB(buf1, WqTall, srow, shalf);               // Wq
  __syncthreads();
  f32x4 qacc[2][8];
  gemm_32x128(buf0, buf1, woff, lr, lg, qacc);
  __syncthreads();                                  // all reads of buf0(As)/buf1(Wq) done
  {
    const float* bq = bqp;
#pragma unroll
    for (int n = 0; n < 8; ++n) {
      const int e = (n << 4) + lr;
      const float bb = bq[e];
#pragma unroll
      for (int mt = 0; mt < 2; ++mt) {
        const int z = (wave << 3) + (mt << 2) + lg;
#pragma unroll
        for (int rr = 0; rr < 4; ++rr)
          buf0[tix((rr << 5) + z, e)] = f2bf(qacc[mt][n][rr] + bb);
      }
    }
  }
  __syncthreads();

  // --- attention (wave handles head dh = wave); E^T = K @ Q^T ---
  bf16x8 ka[2][4], qb2[2][4];
#pragma unroll
  for (int t = 0; t < 2; ++t)
#pragma unroll
    for (int kt = 0; kt < 4; ++kt) {
      const int row = (wave << 5) + (t << 4) + lr;
      const int ks = (kt << 5) + (lg << 3);
      ka[t][kt]  = *(const bf16x8*)&buf2[tix(row, ks)];
      qb2[t][kt] = *(const bf16x8*)&buf0[tix(row, ks)];
    }

  f32x4 et[2][2];
#pragma unroll
  for (int mt = 0; mt < 2; ++mt)
#pragma unroll
    for (int nt = 0; nt < 2; ++nt) et[mt][nt] = (f32x4){0.f, 0.f, 0.f, 0.f};
#pragma unroll
  for (int kt = 0; kt < 4; ++kt)
#pragma unroll
    for (int mt = 0; mt < 2; ++mt)
#pragma unroll
      for (int nt = 0; nt < 2; ++nt)
        et[mt][nt] = mfma16(ka[mt][kt], qb2[nt][kt], et[mt][nt]);

  // softmax over kz (rows of E^T), then /sqrt(128), then *cm  (verified math)
  float p[2][2][4];
#pragma unroll
  for (int nt = 0; nt < 2; ++nt) {
    float mx = -1e30f;
#pragma unroll
    for (int mt = 0; mt < 2; ++mt)
#pragma unroll
      for (int r = 0; r < 4; ++r) mx = fmaxf(mx, et[mt][nt][r]);
    mx = fmaxf(mx, __shfl_xor(mx, 16));
    mx = fmaxf(mx, __shfl_xor(mx, 32));
    float s = 0.f;
#pragma unroll
    for (int mt = 0; mt < 2; ++mt)
#pragma unroll
      for (int r = 0; r < 4; ++r) {
        const float e = __expf(et[mt][nt][r] - mx);
        p[mt][nt][r] = e;
        s += e;
      }
    s += __shfl_xor(s, 16);
    s += __shfl_xor(s, 32);
    const float inv = 1.f / (s * 11.313708498984761f);
    const int qz = (nt << 4) + lr;
#pragma unroll
    for (int mt = 0; mt < 2; ++mt)
#pragma unroll
      for (int r = 0; r < 4; ++r) {
        const int kz = (mt << 4) + (lg << 2) + r;
        const float d = (float)(kz - qz);
        p[mt][nt][r] *= inv * __expf(d * d * (-1.f / 16.f));
      }
  }
  __syncthreads();                                  // all E^T reads of buf2(kL) done

  // P^T -> att[q][kz] in per-wave attL (buf2), chunk-swizzled
  u16* attLb = buf2 + (wave << 10);
#pragma unroll
  for (int nt = 0; nt < 2; ++nt) {
    const int q = (nt << 4) + lr;
    const int qs = (q >> 1) & 3;
#pragma unroll
    for (int mt = 0; mt < 2; ++mt) {
      const int hc = (mt << 2) + lg;               // half-chunk (4 kz)
      const int ch = (hc >> 1) ^ qs;
      const u32 lo = (u32)f2bf(p[mt][nt][0]) | ((u32)f2bf(p[mt][nt][1]) << 16);
      const u32 hi = (u32)f2bf(p[mt][nt][2]) | ((u32)f2bf(p[mt][nt][3]) << 16);
      *(u64*)&attLb[(q << 5) + (ch << 3) + ((hc & 1) << 2)] = (u64)lo | ((u64)hi << 32);
    }
  }

  // PV: out[q][e] = att[q][:] @ V   (vT head = wave)
  bf16x8 pa[2];
#pragma unroll
  for (int mt = 0; mt < 2; ++mt) {
    const int q = (mt << 4) + lr;
    pa[mt] = *(const bf16x8*)&attLb[(q << 5) + ((lg ^ ((q >> 1) & 3)) << 3)];
  }
  f32x4 oacc[2][8];
#pragma unroll
  for (int nt = 0; nt < 8; ++nt) {
    const int e = (nt << 4) + lr;
    const bf16x8 vb = *(const bf16x8*)&buf3[(wave << 12) + (e << 5) + ((lg ^ ((e >> 1) & 3)) << 3)];
#pragma unroll
    for (int mt = 0; mt < 2; ++mt) {
      const f32x4 z4 = (f32x4){0.f, 0.f, 0.f, 0.f};
      oacc[mt][nt] = mfma16(pa[mt], vb, z4);
    }
  }

  // attn-out -> aoutL (buf0, row = qz*4 + head) for the proj GEMM
#pragma unroll
  for (int nt = 0; nt < 8; ++nt) {
    const int e = (nt << 4) + lr;
#pragma unroll
    for (int mt = 0; mt < 2; ++mt)
#pragma unroll
      for (int rr = 0; rr < 4; ++rr) {
        const int q = (mt << 4) + (lg << 2) + rr;
        buf0[tix((q << 2) + wave, e)] = f2bf(oacc[mt][nt][rr]);
      }
  }
  stageB(buf1, WpT, srow, shalf);                   // Wp (overwrites dead Wq)
  __syncthreads();

  // --- proj GEMM + residual + LN2 stats ---
  f32x4 pacc[2][8];
  gemm_32x128(buf0, buf1, woff, lr, lg, pacc);
#pragma unroll
  for (int n = 0; n < 8; ++n) {
    const int col = (n << 4) + lr;
    const float bb = bp[col];
    float ssum = 0.f, qsum = 0.f;
#pragma unroll
    for (int mt = 0; mt < 2; ++mt) {
#pragma unroll
      for (int rr = 0; rr < 4; ++rr) {
        const int rl = woff + (mt << 4) + (lg << 2) + rr;
        const int grow = ((rl >> 2) << 12) + h0 + (rl & 3);
        const size_t gi = ((size_t)grow << 7) + col;
        const float v = pacc[mt][n][rr] + bb + x[gi];
        x[gi] = v;
        ssum += v; qsum += v * v;
      }
    }
    atomicAdd(&sred[col], ssum);
    atomicAdd(&sred[128 + col], qsum);
  }
  __syncthreads();
  atomicAdd(&accum[tid], sred[tid]);
}

// ---------------------------------------------------------------------------
// Fused FFN half-layer: block = 128 consecutive tokens.
//   gemm1 (LN2 folded) -> hswish -> LDS -> gemm2 (accumulate) -> residual ->
//   next-layer LN1 stats.
// ---------------------------------------------------------------------------
__global__ __launch_bounds__(256, 1) void ffn_fused_kernel(
    const u16* __restrict__ W1T,    // [512][128]
    const float* __restrict__ b1,   // [512]
    const u16* __restrict__ W2T,    // [128][512]
    const float* __restrict__ b2,   // [128]
    const float* __restrict__ st,   // [256] LN2 fold
    float* __restrict__ accum,      // [256] next LN1 stats
    float* __restrict__ x)
{
  __shared__ u16 buf0[16384];  // As
  __shared__ u16 buf1[16384];  // Bs: W1 chunk / W2 chunk
  __shared__ u16 buf2[16384];  // hL
  __shared__ float sred[256];

  const int tid = threadIdx.x;
  const int lane = tid & 63, wave = tid >> 6;
  const int lr = lane & 15, lg = lane >> 4;
  const int srow = tid >> 1, shalf = tid & 1;
  const int r0 = blockIdx.x << 7;
  const int woff = wave << 5;

  sred[tid] = 0.f;

  // stage A (LN2-folded bf16)
  {
    const float* xr = x + (((size_t)(r0 + srow)) << 7) + (shalf << 6);
    const int s0 = shalf << 6;
#pragma unroll
    for (int cc = 0; cc < 8; ++cc) {
      fvec4 v0 = *(const fvec4*)(xr + cc * 8);
      fvec4 v1 = *(const fvec4*)(xr + cc * 8 + 4);
      fvec4 sA = *(const fvec4*)(st + s0 + cc * 8);
      fvec4 sB = *(const fvec4*)(st + s0 + cc * 8 + 4);
      fvec4 tA = *(const fvec4*)(st + 128 + s0 + cc * 8);
      fvec4 tB = *(const fvec4*)(st + 128 + s0 + cc * 8 + 4);
      bf16x8 w;
#pragma unroll
      for (int j = 0; j < 4; ++j) w[j] = (short)f2bf(v0[j] * sA[j] + tA[j]);
#pragma unroll
      for (int j = 0; j < 4; ++j) w[4 + j] = (short)f2bf(v1[j] * sB[j] + tB[j]);
      *(bf16x8*)&buf0[tix(srow, s0 + cc * 8)] = w;
    }
  }

  f32x4 acc2[2][8];
#pragma unroll
  for (int mt = 0; mt < 2; ++mt)
#pragma unroll
    for (int n = 0; n < 8; ++n) acc2[mt][n] = (f32x4){0.f, 0.f, 0.f, 0.f};

  for (int c = 0; c < 4; ++c) {
    __syncthreads();                                // prev gemm2 / As staging done
    stageB(buf1, W1T + (c << 14), srow, shalf);     // W1 chunk c
    __syncthreads();
    f32x4 a1[2][8];
    gemm_32x128(buf0, buf1, woff, lr, lg, a1);
    // h = hswish(a1 + b1) -> hL
#pragma unroll
    for (int n = 0; n < 8; ++n) {
      const float bb = b1[(c << 7) + (n << 4) + lr];
#pragma unroll
      for (int mt = 0; mt < 2; ++mt)
#pragma unroll
        for (int rr = 0; rr < 4; ++rr) {
          const int rl = woff + (mt << 4) + (lg << 2) + rr;
          const float h = a1[mt][n][rr] + bb;
          const float r6 = fminf(fmaxf(h + 3.f, 0.f), 6.f);
          buf2[tix(rl, (n << 4) + lr)] = f2bf(h * r6 * (1.f / 6.f));
        }
    }
    __syncthreads();                                // hL ready, gemm1's buf1 reads done
    {
      const u16* br = W2T + (srow << 9) + (c << 7) + (shalf << 6);
#pragma unroll
      for (int cc = 0; cc < 8; ++cc)
        *(bf16x8*)&buf1[tix(srow, (shalf << 6) + cc * 8)] = *(const bf16x8*)(br + cc * 8);
    }
    __syncthreads();
    // gemm2: acc2 += hL @ W2c
#pragma unroll
    for (int kk = 0; kk < 4; ++kk) {
      bf16x8 af[2], bfr[8];
      const int ks = (kk << 5) + (lg << 3);
#pragma unroll
      for (int mt = 0; mt < 2; ++mt)
        af[mt] = *(const bf16x8*)&buf2[tix(woff + (mt << 4) + lr, ks)];
#pragma unroll
      for (int n = 0; n < 8; ++n)
        bfr[n] = *(const bf16x8*)&buf1[tix((n << 4) + lr, ks)];
#pragma unroll
      for (int mt = 0; mt < 2; ++mt)
#pragma unroll
        for (int n = 0; n < 8; ++n)
          acc2[mt][n] = mfma16(af[mt], bfr[n], acc2[mt][n]);
    }
  }

  // epilogue: residual + store + stats
#pragma unroll
  for (int n = 0; n < 8; ++n) {
    const int col = (n << 4) + lr;
    const float bb = b2[col];
    float ssum = 0.f, qsum = 0.f;
#pragma unroll
    for (int mt = 0; mt < 2; ++mt) {
#pragma unroll
      for (int rr = 0; rr < 4; ++rr) {
        const int rl = woff + (mt << 4) + (lg << 2) + rr;
        const size_t gi = ((size_t)(r0 + rl) << 7) + col;
        const float v = acc2[mt][n][rr] + bb + x[gi];
        x[gi] = v;
        ssum += v; qsum += v * v;
      }
    }
    atomicAdd(&sred[col], ssum);
    atomicAdd(&sred[128 + col], qsum);
  }
  __syncthreads();
  atomicAdd(&accum[tid], sred[tid]);
}

// ---------------------------------------------------------------------------
extern "C" void kernel_launch(void* const* d_in, const int* in_sizes, int n_in,
                              void* d_out, int out_size, void* d_ws, size_t ws_size,
                              hipStream_t stream)
{
  const float* img   = (const float*)d_in[0];
  const float* ln1g  = (const float*)d_in[1];
  const float* ln1b  = (const float*)d_in[2];
  const float* Wqkv  = (const float*)d_in[3];
  const float* bqkv  = (const float*)d_in[4];
  const float* Wproj = (const float*)d_in[5];
  const float* bproj = (const float*)d_in[6];
  const float* ln2g  = (const float*)d_in[7];
  const float* ln2b  = (const float*)d_in[8];
  const float* W1    = (const float*)d_in[9];
  const float* b1    = (const float*)d_in[10];
  const float* W2    = (const float*)d_in[11];
  const float* b2    = (const float*)d_in[12];

  char* ws = (char*)d_ws;
  float* x = (float*)ws;                              // 64 MB
  char* wsw = ws + ((size_t)64 << 20);
  u16* WqT = (u16*)wsw;                               // 3*49152
  u16* WpT = WqT + 3 * 49152;                         // 3*16384
  u16* W1T = WpT + 3 * 16384;                         // 3*65536
  u16* W2T = W1T + 3 * 65536;                         // 3*65536
  float* bqp = (float*)(W2T + 3 * 65536);             // 3*384
  float* A   = bqp + 3 * 384;                         // 7*256 stats accumulators
  float* S   = A + 7 * 256;                           // 7*256 fold params

  prep_kernel<<<2309, 256, 0, stream>>>(Wqkv, bqkv, Wproj, W1, W2, WqT, WpT, W1T, W2T, bqp);
  tin_kernel<<<2048, 256, 0, stream>>>(img, x);
  hipMemsetAsync(A, 0, 7 * 256 * sizeof(float), stream);
  colstats_kernel<<<512, 256, 0, stream>>>(x, A);
  finalize_kernel<<<1, 128, 0, stream>>>(A, ln1g, ln1b, S);

  for (int d = 0; d < 3; ++d) {
    float* accA = A + (2 * d + 1) * 256;
    float* accF = A + (2 * d + 2) * 256;
    float* st1  = S + (2 * d) * 256;
    float* st2  = S + (2 * d + 1) * 256;
    attn_fused_kernel<<<1024, 256, 0, stream>>>(
        WqT + d * 49152, bqp + d * 384, WpT + d * 16384, bproj + d * 128,
        st1, accA, x);
    finalize_kernel<<<1, 128, 0, stream>>>(accA, ln2g + d * 128, ln2b + d * 128, st2);
    ffn_fused_kernel<<<1024, 256, 0, stream>>>(
        W1T + d * 65536, b1 + d * 512, W2T + d * 65536, b2 + d * 128,
        st2, accF, x);
    if (d < 2)
      finalize_kernel<<<1, 128, 0, stream>>>(accF, ln1g + (d + 1) * 128, ln1b + (d + 1) * 128,
                                             S + (2 * d + 2) * 256);
  }

  tout_kernel<<<2048, 256, 0, stream>>>(x, (float*)d_out);
}

// Round 3
// 810.134 us; speedup vs baseline: 1.5186x; 1.2307x over previous
//
#include <hip/hip_runtime.h>
#include <hip/hip_bf16.h>

typedef __attribute__((ext_vector_type(8))) short bf16x8;
typedef __attribute__((ext_vector_type(4))) float f32x4;
typedef __attribute__((ext_vector_type(4))) float fvec4;
typedef unsigned short u16;
typedef unsigned int u32;
typedef unsigned long long u64;

#define N_TOK 131072

__device__ __forceinline__ u16 f2bf(float f) {
  u32 u = __builtin_bit_cast(u32, f);
  u += 0x7FFFu + ((u >> 16) & 1u);          // round-to-nearest-even
  return (u16)(u >> 16);
}

__device__ __forceinline__ f32x4 mfma16(bf16x8 a, bf16x8 b, f32x4 c) {
  return __builtin_amdgcn_mfma_f32_16x16x32_bf16(a, b, c, 0, 0, 0);
}

// swizzled index into [rows][128 shorts] LDS tile: 16B-chunk XOR row&15
__device__ __forceinline__ int tix(int row, int s) {
  return (row << 7) + ((((s >> 3) ^ (row & 15))) << 3) + (s & 7);
}
// swizzled index into [rows][64 shorts] LDS tile: 16B-chunk XOR row&7
__device__ __forceinline__ int tix64(int row, int s) {
  return (row << 6) + ((((s >> 3) ^ (row & 7))) << 3) + (s & 7);
}

// ---------------------------------------------------------------------------
// Weight prep (unchanged, verified)
// ---------------------------------------------------------------------------
__global__ __launch_bounds__(256) void prep_kernel(
    const float* __restrict__ Wqkv, const float* __restrict__ bqkv,
    const float* __restrict__ Wproj, const float* __restrict__ W1,
    const float* __restrict__ W2,
    u16* __restrict__ WqT, u16* __restrict__ WpT,
    u16* __restrict__ W1T, u16* __restrict__ W2T,
    float* __restrict__ bqp)
{
  const int idx = blockIdx.x * 256 + threadIdx.x;
  const int PER = 196608;
  if (idx < 3 * PER) {
    const int d = idx / PER, r = idx % PER;
    if (r < 49152) {                       // WqT[d][384][128]
      const int c = r >> 7, k = r & 127;
      WqT[d * 49152 + r] = f2bf(Wqkv[(size_t)d * 49152 + k * 384 + ((c & 127) * 3 + (c >> 7))]);
    } else if (r < 65536) {                // WpT[d][128][128]
      const int r2 = r - 49152; const int c = r2 >> 7, k = r2 & 127;
      WpT[d * 16384 + r2] = f2bf(Wproj[(size_t)d * 16384 + k * 128 + c]);
    } else if (r < 131072) {               // W1T[d][512][128]
      const int r3 = r - 65536; const int c = r3 >> 7, k = r3 & 127;
      W1T[d * 65536 + r3] = f2bf(W1[(size_t)d * 65536 + k * 512 + c]);
    } else {                               // W2T[d][128][512]
      const int r4 = r - 131072; const int c = r4 >> 9, k = r4 & 511;
      W2T[d * 65536 + r4] = f2bf(W2[(size_t)d * 65536 + k * 128 + c]);
    }
  } else if (idx < 3 * PER + 1152) {
    const int i2 = idx - 3 * PER; const int d = i2 / 384, c = i2 % 384;
    bqp[i2] = bqkv[d * 384 + (c & 127) * 3 + (c >> 7)];
  }
}

// ---------------------------------------------------------------------------
// img [128][131072] f32 -> x [131072][128] f32, with fused LN1-layer0 stats
// ---------------------------------------------------------------------------
__global__ __launch_bounds__(256) void tin_kernel(const float* __restrict__ img,
                                                  float* __restrict__ x,
                                                  float* __restrict__ accum)
{
  __shared__ float t[128 * 65];
  __shared__ float ssum[256], sqq[256];
  const int t0 = blockIdx.x * 64;
  const int tid = threadIdx.x;
  {
    const int j = tid & 63, cq = tid >> 6;
    for (int c = cq; c < 128; c += 4) t[c * 65 + j] = img[(size_t)c * N_TOK + t0 + j];
  }
  __syncthreads();
  {
    const int c = tid & 127, jh = tid >> 7;
    float s = 0.f, q = 0.f;
    for (int jj = jh; jj < 64; jj += 2) {
      const float v = t[c * 65 + jj];
      x[(size_t)(t0 + jj) * 128 + c] = v;
      s += v; q += v * v;
    }
    ssum[tid] = s; sqq[tid] = q;
  }
  __syncthreads();
  if (tid < 128) {
    atomicAdd(&accum[tid], ssum[tid] + ssum[tid + 128]);
    atomicAdd(&accum[128 + tid], sqq[tid] + sqq[tid + 128]);
  }
}

// x [131072][128] -> out [128][131072] with relu
__global__ __launch_bounds__(256) void tout_kernel(const float* __restrict__ x,
                                                   float* __restrict__ out)
{
  __shared__ float t[128 * 65];
  const int t0 = blockIdx.x * 64;
  const int tid = threadIdx.x;
  {
    const int c = tid & 127, jh = tid >> 7;
    for (int jj = jh; jj < 64; jj += 2) t[c * 65 + jj] = x[(size_t)(t0 + jj) * 128 + c];
  }
  __syncthreads();
  {
    const int j = tid & 63, cq = tid >> 6;
    for (int c = cq; c < 128; c += 4)
      out[(size_t)c * N_TOK + t0 + j] = fmaxf(t[c * 65 + j], 0.f);
  }
}

__global__ void finalize_kernel(const float* __restrict__ accum, const float* __restrict__ g,
                                const float* __restrict__ b, float* __restrict__ st)
{
  const int c = threadIdx.x;
  const float inv = 1.f / 131072.f;
  const float mu = accum[c] * inv;
  const float var = accum[128 + c] * inv - mu * mu;
  const float s = g[c] * rsqrtf(var + 1e-5f);
  st[c] = s;
  st[128 + c] = b[c] - mu * s;
}

// ---------------------------------------------------------------------------
// Device helpers
// ---------------------------------------------------------------------------
// load wave's A fragments (2 rows/lane x 32 k strided) from global with LN fold
__device__ __forceinline__ void ln_load_afrags(const float* __restrict__ x0,
                                               const float* __restrict__ x1,
                                               const float* __restrict__ st,
                                               int lg, bf16x8 aF[2][4]) {
#pragma unroll
  for (int kk = 0; kk < 4; ++kk) {
    const int k0 = (kk << 5) + (lg << 3);
    const fvec4 sA = *(const fvec4*)(st + k0);
    const fvec4 sB = *(const fvec4*)(st + k0 + 4);
    const fvec4 tA = *(const fvec4*)(st + 128 + k0);
    const fvec4 tB = *(const fvec4*)(st + 128 + k0 + 4);
    {
      const fvec4 v0 = *(const fvec4*)(x0 + k0);
      const fvec4 v1 = *(const fvec4*)(x0 + k0 + 4);
      bf16x8 w;
#pragma unroll
      for (int j = 0; j < 4; ++j) w[j] = (short)f2bf(v0[j] * sA[j] + tA[j]);
#pragma unroll
      for (int j = 0; j < 4; ++j) w[4 + j] = (short)f2bf(v1[j] * sB[j] + tB[j]);
      aF[0][kk] = w;
    }
    {
      const fvec4 v0 = *(const fvec4*)(x1 + k0);
      const fvec4 v1 = *(const fvec4*)(x1 + k0 + 4);
      bf16x8 w;
#pragma unroll
      for (int j = 0; j < 4; ++j) w[j] = (short)f2bf(v0[j] * sA[j] + tA[j]);
#pragma unroll
      for (int j = 0; j < 4; ++j) w[4 + j] = (short)f2bf(v1[j] * sB[j] + tB[j]);
      aF[1][kk] = w;
    }
  }
}

// stage [64 rows][128 shorts] contiguous chunk -> tix-swizzled LDS
__device__ __forceinline__ void stage64x128(u16* __restrict__ dst, const u16* __restrict__ src,
                                            int tid) {
  const int row = tid >> 2, q = tid & 3;
  const u16* s = src + (row << 7) + (q << 5);
#pragma unroll
  for (int j = 0; j < 4; ++j)
    *(bf16x8*)&dst[tix(row, (q << 5) + (j << 3))] = *(const bf16x8*)(s + (j << 3));
}

// stage [128 rows][64 shorts] (strided rows) -> tix64-swizzled LDS
__device__ __forceinline__ void stage128x64(u16* __restrict__ dst, const u16* __restrict__ src,
                                            int rowstride, int tid) {
  const int row = tid >> 1, h = tid & 1;
  const u16* s = src + row * rowstride + (h << 5);
#pragma unroll
  for (int j = 0; j < 4; ++j)
    *(bf16x8*)&dst[tix64(row, (h << 5) + (j << 3))] = *(const bf16x8*)(s + (j << 3));
}

// acc[2][4] = Aregs(32 rows x 128k) @ B-chunk(64 cols x 128k, tix)
__device__ __forceinline__ void gemm_rA_B64(const bf16x8 aF[2][4], const u16* __restrict__ B,
                                            int lr, int lg, f32x4 acc[2][4]) {
#pragma unroll
  for (int mt = 0; mt < 2; ++mt)
#pragma unroll
    for (int n = 0; n < 4; ++n) acc[mt][n] = (f32x4){0.f, 0.f, 0.f, 0.f};
#pragma unroll
  for (int kk = 0; kk < 4; ++kk) {
    const int ks = (kk << 5) + (lg << 3);
    bf16x8 bfr[4];
#pragma unroll
    for (int n = 0; n < 4; ++n)
      bfr[n] = *(const bf16x8*)&B[tix((n << 4) + lr, ks)];
#pragma unroll
    for (int mt = 0; mt < 2; ++mt)
#pragma unroll
      for (int n = 0; n < 4; ++n)
        acc[mt][n] = mfma16(aF[mt][kk], bfr[n], acc[mt][n]);
  }
}

// acc[2][8] += A[128 rows][64 k](tix64, wave rows woff..) @ B[128 cols][64 k](tix64)
__device__ __forceinline__ void gemm_A64_B128(const u16* __restrict__ A, const u16* __restrict__ B,
                                              int woff, int lr, int lg, f32x4 acc[2][8]) {
#pragma unroll
  for (int kk = 0; kk < 2; ++kk) {
    const int ks = (kk << 5) + (lg << 3);
    bf16x8 af[2], bfr[8];
#pragma unroll
    for (int mt = 0; mt < 2; ++mt)
      af[mt] = *(const bf16x8*)&A[tix64(woff + (mt << 4) + lr, ks)];
#pragma unroll
    for (int n = 0; n < 8; ++n)
      bfr[n] = *(const bf16x8*)&B[tix64((n << 4) + lr, ks)];
#pragma unroll
    for (int mt = 0; mt < 2; ++mt)
#pragma unroll
      for (int n = 0; n < 8; ++n)
        acc[mt][n] = mfma16(af[mt], bfr[n], acc[mt][n]);
  }
}

// ---------------------------------------------------------------------------
// Fused attention half-layer: block = 4 heads x 32 z = 128 tokens, 4 waves.
// LDS 65 KB -> 2 blocks/CU. A in registers.
// ---------------------------------------------------------------------------
__global__ __launch_bounds__(256) void attn_fused_kernel(
    const u16* __restrict__ WqTall,       // [384][128]: Wq rows 0-127, Wk 128-255, Wv 256-383
    const float* __restrict__ bqp,        // [384]
    const u16* __restrict__ WpT,          // [128][128]
    const float* __restrict__ bp,         // [128]
    const float* __restrict__ st,         // [256] LN1 fold
    float* __restrict__ accum,            // [256] LN2 stats out
    float* __restrict__ x)                // [131072][128] read + update
{
  __shared__ u16 L0[8192];   // W chunks
  __shared__ u16 L1[8192];   // kL-half -> attL (per-wave)
  __shared__ u16 L2[8192];   // qL-half -> vT-half
  __shared__ u16 L3[8192];   // aout-half
  __shared__ float sred[256];

  const int tid = threadIdx.x;
  const int lane = tid & 63, wave = tid >> 6;
  const int lr = lane & 15, lg = lane >> 4;
  const int h0 = blockIdx.x << 2;
  const int woff = wave << 5;

  sred[tid] = 0.f;

  // A fragments in registers (LN1-folded)
  const int r0a = woff + lr, r1a = woff + 16 + lr;
  const int g0 = ((r0a >> 2) << 12) + h0 + (r0a & 3);
  const int g1 = ((r1a >> 2) << 12) + h0 + (r1a & 3);
  bf16x8 aF[2][4];
  ln_load_afrags(x + ((size_t)g0 << 7), x + ((size_t)g1 << 7), st, lg, aF);

  // --- QK phase: E^T accumulated over two 64-e halves ---
  f32x4 et[2][2];
#pragma unroll
  for (int mt = 0; mt < 2; ++mt)
#pragma unroll
    for (int nt = 0; nt < 2; ++nt) et[mt][nt] = (f32x4){0.f, 0.f, 0.f, 0.f};

  for (int eh = 0; eh < 2; ++eh) {
    stage64x128(L0, WqTall + 16384 + (eh << 13), tid);   // Wk half
    __syncthreads();
    {
      f32x4 kacc[2][4];
      gemm_rA_B64(aF, L0, lr, lg, kacc);
      const float* bk = bqp + 128 + (eh << 6);
#pragma unroll
      for (int n = 0; n < 4; ++n) {
        const int el = (n << 4) + lr;
        const float bb = bk[el];
#pragma unroll
        for (int mt = 0; mt < 2; ++mt)
#pragma unroll
          for (int rr = 0; rr < 4; ++rr) {
            const int R = (rr << 5) + (wave << 3) + (mt << 2) + lg;  // head*32+z
            L1[tix64(R, el)] = f2bf(kacc[mt][n][rr] + bb);
          }
      }
    }
    __syncthreads();
    stage64x128(L0, WqTall + (eh << 13), tid);            // Wq half
    __syncthreads();
    {
      f32x4 qacc[2][4];
      gemm_rA_B64(aF, L0, lr, lg, qacc);
      const float* bq = bqp + (eh << 6);
#pragma unroll
      for (int n = 0; n < 4; ++n) {
        const int el = (n << 4) + lr;
        const float bb = bq[el];
#pragma unroll
        for (int mt = 0; mt < 2; ++mt)
#pragma unroll
          for (int rr = 0; rr < 4; ++rr) {
            const int R = (rr << 5) + (wave << 3) + (mt << 2) + lg;
            L2[tix64(R, el)] = f2bf(qacc[mt][n][rr] + bb);
          }
      }
    }
    __syncthreads();
    // E^T partial over this e-half (head = wave)
    bf16x8 ka[2][2], qb2[2][2];
#pragma unroll
    for (int t = 0; t < 2; ++t)
#pragma unroll
      for (int kt = 0; kt < 2; ++kt) {
        const int row = (wave << 5) + (t << 4) + lr;
        const int ks = (kt << 5) + (lg << 3);
        ka[t][kt]  = *(const bf16x8*)&L1[tix64(row, ks)];
        qb2[t][kt] = *(const bf16x8*)&L2[tix64(row, ks)];
      }
#pragma unroll
    for (int kt = 0; kt < 2; ++kt)
#pragma unroll
      for (int mt = 0; mt < 2; ++mt)
#pragma unroll
        for (int nt = 0; nt < 2; ++nt)
          et[mt][nt] = mfma16(ka[mt][kt], qb2[nt][kt], et[mt][nt]);
  }

  // --- softmax over kz, /sqrt(128), *cm (verified math) ---
  float p[2][2][4];
#pragma unroll
  for (int nt = 0; nt < 2; ++nt) {
    float mx = -1e30f;
#pragma unroll
    for (int mt = 0; mt < 2; ++mt)
#pragma unroll
      for (int r = 0; r < 4; ++r) mx = fmaxf(mx, et[mt][nt][r]);
    mx = fmaxf(mx, __shfl_xor(mx, 16));
    mx = fmaxf(mx, __shfl_xor(mx, 32));
    float s = 0.f;
#pragma unroll
    for (int mt = 0; mt < 2; ++mt)
#pragma unroll
      for (int r = 0; r < 4; ++r) {
        const float e = __expf(et[mt][nt][r] - mx);
        p[mt][nt][r] = e;
        s += e;
      }
    s += __shfl_xor(s, 16);
    s += __shfl_xor(s, 32);
    const float inv = 1.f / (s * 11.313708498984761f);
    const int qz = (nt << 4) + lr;
#pragma unroll
    for (int mt = 0; mt < 2; ++mt)
#pragma unroll
      for (int r = 0; r < 4; ++r) {
        const int kz = (mt << 4) + (lg << 2) + r;
        const float d = (float)(kz - qz);
        p[mt][nt][r] *= inv * __expf(d * d * (-1.f / 16.f));
      }
  }

  // P^T -> attL[q][kz] in wave's own region of L1 (rows wave*32.., same as read)
  u16* attLb = L1 + (wave << 11);
#pragma unroll
  for (int nt = 0; nt < 2; ++nt) {
    const int q = (nt << 4) + lr;
    const int qs = (q >> 1) & 3;
#pragma unroll
    for (int mt = 0; mt < 2; ++mt) {
      const int hc = (mt << 2) + lg;
      const int ch = (hc >> 1) ^ qs;
      const u32 lo = (u32)f2bf(p[mt][nt][0]) | ((u32)f2bf(p[mt][nt][1]) << 16);
      const u32 hi = (u32)f2bf(p[mt][nt][2]) | ((u32)f2bf(p[mt][nt][3]) << 16);
      *(u64*)&attLb[(q << 5) + (ch << 3) + ((hc & 1) << 2)] = (u64)lo | ((u64)hi << 32);
    }
  }
  bf16x8 pa[2];
#pragma unroll
  for (int mt = 0; mt < 2; ++mt) {
    const int q = (mt << 4) + lr;
    pa[mt] = *(const bf16x8*)&attLb[(q << 5) + ((lg ^ ((q >> 1) & 3)) << 3)];
  }

  // --- V / PV / proj phase, two 64-e halves ---
  f32x4 pacc[2][8];
#pragma unroll
  for (int mt = 0; mt < 2; ++mt)
#pragma unroll
    for (int n = 0; n < 8; ++n) pacc[mt][n] = (f32x4){0.f, 0.f, 0.f, 0.f};

  for (int vh = 0; vh < 2; ++vh) {
    stage64x128(L0, WqTall + 32768 + (vh << 13), tid);    // Wv half
    __syncthreads();   // also guarantees all waves done with E^T reads of L2
    {
      f32x4 vacc[2][4];
      gemm_rA_B64(aF, L0, lr, lg, vacc);
      const float* bv = bqp + 256 + (vh << 6);
#pragma unroll
      for (int n = 0; n < 4; ++n) {
        const int el = (n << 4) + lr;
        const float bb = bv[el];
        const int sw = (el >> 1) & 3;
#pragma unroll
        for (int mt = 0; mt < 2; ++mt) {
          const int kzl = (mt << 2) + lg;                  // kz = wave*8 + kzl
#pragma unroll
          for (int rr = 0; rr < 4; ++rr)                   // head = rr
            L2[(rr << 11) + (el << 5) + ((wave ^ sw) << 3) + kzl] = f2bf(vacc[mt][n][rr] + bb);
        }
      }
    }
    __syncthreads();
    // PV half: out[q][el] (head = wave)
    f32x4 oacc[2][4];
#pragma unroll
    for (int n = 0; n < 4; ++n) {
      const int el = (n << 4) + lr;
      const bf16x8 vb = *(const bf16x8*)&L2[(wave << 11) + (el << 5) + ((lg ^ ((el >> 1) & 3)) << 3)];
#pragma unroll
      for (int mt = 0; mt < 2; ++mt) {
        const f32x4 z4 = (f32x4){0.f, 0.f, 0.f, 0.f};
        oacc[mt][n] = mfma16(pa[mt], vb, z4);
      }
    }
    // aout half -> L3 (srow = z*4 + head)
#pragma unroll
    for (int n = 0; n < 4; ++n) {
      const int el = (n << 4) + lr;
#pragma unroll
      for (int mt = 0; mt < 2; ++mt)
#pragma unroll
        for (int rr = 0; rr < 4; ++rr) {
          const int q = (mt << 4) + (lg << 2) + rr;
          L3[tix64((q << 2) + wave, el)] = f2bf(oacc[mt][n][rr]);
        }
    }
    stage128x64(L0, WpT + (vh << 6), 128, tid);           // Wp k-half
    __syncthreads();
    gemm_A64_B128(L3, L0, woff, lr, lg, pacc);            // proj partial (k=64)
    __syncthreads();
  }

  // --- epilogue: residual + LN2 stats ---
#pragma unroll
  for (int n = 0; n < 8; ++n) {
    const int col = (n << 4) + lr;
    const float bb = bp[col];
    float ssum = 0.f, qsum = 0.f;
#pragma unroll
    for (int mt = 0; mt < 2; ++mt) {
#pragma unroll
      for (int rr = 0; rr < 4; ++rr) {
        const int rl = woff + (mt << 4) + (lg << 2) + rr;
        const int grow = ((rl >> 2) << 12) + h0 + (rl & 3);
        const size_t gi = ((size_t)grow << 7) + col;
        const float v = pacc[mt][n][rr] + bb + x[gi];
        x[gi] = v;
        ssum += v; qsum += v * v;
      }
    }
    atomicAdd(&sred[col], ssum);
    atomicAdd(&sred[128 + col], qsum);
  }
  __syncthreads();
  atomicAdd(&accum[tid], sred[tid]);
}

// ---------------------------------------------------------------------------
// Fused FFN half-layer: block = 128 consecutive tokens, 4 waves, LDS 49 KB.
// 8 chunks of 64 h-cols; h never leaves the block; A in registers.
// ---------------------------------------------------------------------------
__global__ __launch_bounds__(256) void ffn_fused_kernel(
    const u16* __restrict__ W1T,    // [512][128]
    const float* __restrict__ b1,   // [512]
    const u16* __restrict__ W2T,    // [128][512]
    const float* __restrict__ b2,   // [128]
    const float* __restrict__ st,   // [256] LN2 fold
    float* __restrict__ accum,      // [256] next LN1 stats
    float* __restrict__ x)
{
  __shared__ u16 LW1[8192];  // W1 chunk [64][128]
  __shared__ u16 LW2[8192];  // W2 chunk [128][64]
  __shared__ u16 LH[8192];   // h chunk  [128][64]
  __shared__ float sred[256];

  const int tid = threadIdx.x;
  const int lane = tid & 63, wave = tid >> 6;
  const int lr = lane & 15, lg = lane >> 4;
  const int r0 = blockIdx.x << 7;
  const int woff = wave << 5;

  sred[tid] = 0.f;

  // A fragments in registers (LN2-folded); wave rows are contiguous
  const int gr0 = r0 + woff + lr;
  bf16x8 aF[2][4];
  ln_load_afrags(x + ((size_t)gr0 << 7), x + ((size_t)(gr0 + 16) << 7), st, lg, aF);

  f32x4 acc2[2][8];
#pragma unroll
  for (int mt = 0; mt < 2; ++mt)
#pragma unroll
    for (int n = 0; n < 8; ++n) acc2[mt][n] = (f32x4){0.f, 0.f, 0.f, 0.f};

  for (int c = 0; c < 8; ++c) {
    stage64x128(LW1, W1T + (c << 13), tid);
    stage128x64(LW2, W2T + (c << 6), 512, tid);
    __syncthreads();
    f32x4 a1[2][4];
    gemm_rA_B64(aF, LW1, lr, lg, a1);
    // h = hswish(a1 + b1) -> LH (own-wave rows; no barrier needed before gemm2)
    const float* bb1 = b1 + (c << 6);
#pragma unroll
    for (int n = 0; n < 4; ++n) {
      const int hl = (n << 4) + lr;
      const float bb = bb1[hl];
#pragma unroll
      for (int mt = 0; mt < 2; ++mt)
#pragma unroll
        for (int rr = 0; rr < 4; ++rr) {
          const int rl = woff + (mt << 4) + (lg << 2) + rr;
          const float h = a1[mt][n][rr] + bb;
          const float r6 = fminf(fmaxf(h + 3.f, 0.f), 6.f);
          LH[tix64(rl, hl)] = f2bf(h * r6 * (1.f / 6.f));
        }
    }
    gemm_A64_B128(LH, LW2, woff, lr, lg, acc2);   // k=64 partial
    __syncthreads();
  }

  // epilogue: residual + next LN1 stats
#pragma unroll
  for (int n = 0; n < 8; ++n) {
    const int col = (n << 4) + lr;
    const float bb = b2[col];
    float ssum = 0.f, qsum = 0.f;
#pragma unroll
    for (int mt = 0; mt < 2; ++mt) {
#pragma unroll
      for (int rr = 0; rr < 4; ++rr) {
        const int rl = woff + (mt << 4) + (lg << 2) + rr;
        const size_t gi = ((size_t)(r0 + rl) << 7) + col;
        const float v = acc2[mt][n][rr] + bb + x[gi];
        x[gi] = v;
        ssum += v; qsum += v * v;
      }
    }
    atomicAdd(&sred[col], ssum);
    atomicAdd(&sred[128 + col], qsum);
  }
  __syncthreads();
  atomicAdd(&accum[tid], sred[tid]);
}

// ---------------------------------------------------------------------------
extern "C" void kernel_launch(void* const* d_in, const int* in_sizes, int n_in,
                              void* d_out, int out_size, void* d_ws, size_t ws_size,
                              hipStream_t stream)
{
  const float* img   = (const float*)d_in[0];
  const float* ln1g  = (const float*)d_in[1];
  const float* ln1b  = (const float*)d_in[2];
  const float* Wqkv  = (const float*)d_in[3];
  const float* bqkv  = (const float*)d_in[4];
  const float* Wproj = (const float*)d_in[5];
  const float* bproj = (const float*)d_in[6];
  const float* ln2g  = (const float*)d_in[7];
  const float* ln2b  = (const float*)d_in[8];
  const float* W1    = (const float*)d_in[9];
  const float* b1    = (const float*)d_in[10];
  const float* W2    = (const float*)d_in[11];
  const float* b2    = (const float*)d_in[12];

  char* ws = (char*)d_ws;
  float* x = (float*)ws;                              // 64 MB
  char* wsw = ws + ((size_t)64 << 20);
  u16* WqT = (u16*)wsw;                               // 3*49152
  u16* WpT = WqT + 3 * 49152;                         // 3*16384
  u16* W1T = WpT + 3 * 16384;                         // 3*65536
  u16* W2T = W1T + 3 * 65536;                         // 3*65536
  float* bqp = (float*)(W2T + 3 * 65536);             // 3*384
  float* A   = bqp + 3 * 384;                         // 7*256 stats accumulators
  float* S   = A + 7 * 256;                           // 7*256 fold params

  prep_kernel<<<2309, 256, 0, stream>>>(Wqkv, bqkv, Wproj, W1, W2, WqT, WpT, W1T, W2T, bqp);
  hipMemsetAsync(A, 0, 7 * 256 * sizeof(float), stream);
  tin_kernel<<<2048, 256, 0, stream>>>(img, x, A);
  finalize_kernel<<<1, 128, 0, stream>>>(A, ln1g, ln1b, S);

  for (int d = 0; d < 3; ++d) {
    float* accA = A + (2 * d + 1) * 256;
    float* accF = A + (2 * d + 2) * 256;
    float* st1  = S + (2 * d) * 256;
    float* st2  = S + (2 * d + 1) * 256;
    attn_fused_kernel<<<1024, 256, 0, stream>>>(
        WqT + d * 49152, bqp + d * 384, WpT + d * 16384, bproj + d * 128,
        st1, accA, x);
    finalize_kernel<<<1, 128, 0, stream>>>(accA, ln2g + d * 128, ln2b + d * 128, st2);
    ffn_fused_kernel<<<1024, 256, 0, stream>>>(
        W1T + d * 65536, b1 + d * 512, W2T + d * 65536, b2 + d * 128,
        st2, accF, x);
    if (d < 2)
      finalize_kernel<<<1, 128, 0, stream>>>(accF, ln1g + (d + 1) * 128, ln1b + (d + 1) * 128,
                                             S + (2 * d + 2) * 256);
  }

  tout_kernel<<<2048, 256, 0, stream>>>(x, (float*)d_out);
}